// Round 2
// baseline (462.173 us; speedup 1.0000x reference)
//
#include <hip/hip_runtime.h>
#include <hip/hip_fp16.h>

#define NN 100000
#define NE 3200000
#define FIN 300
#define HID 16
#define NC 10

#define NPB 64                  // nodes per bucket
#define NB 1563                 // ceil(NN / NPB)
#define NSEG 512                // edge segments
#define EPS (NE / NSEG)         // 6250 edges per segment
#define NCH 8                   // chunks for the seg-scan
#define SEGPC (NSEG / NCH)      // 64 segs per chunk
#define CAP 4096                // max bucket size (mean 2048, sd ~45)

__device__ __forceinline__ float h2f_lo(int y) {
    __half_raw hr; hr.x = (unsigned short)(y & 0xFFFF);
    __half h; *(__half_raw*)&h = hr;
    return __half2float(h);
}
__device__ __forceinline__ int f2h_us(float f) {
    __half h = __float2half(f);
    return (int)(*(__half_raw*)&h).x;
}

// wave-uniform pointer hoist: makes the compiler scalarize (s_load) W reads
__device__ __forceinline__ const float* rfl_cfp(const float* p) {
    unsigned long long u = (unsigned long long)p;
    unsigned lo = __builtin_amdgcn_readfirstlane((unsigned)(u & 0xFFFFFFFFull));
    unsigned hi = __builtin_amdgcn_readfirstlane((unsigned)(u >> 32));
    return (const float*)((((unsigned long long)hi) << 32) | (unsigned long long)lo);
}

// ---- phase 1: per-segment histogram over buckets ---------------------------

__global__ void k_hist(const int* __restrict__ col, int* __restrict__ hist) {
    __shared__ int bins[NB];
    int seg = blockIdx.x, tid = threadIdx.x;
    for (int i = tid; i < NB; i += 256) bins[i] = 0;
    __syncthreads();
    int base = seg * EPS;
    for (int k = tid; k < EPS; k += 256) atomicAdd(&bins[col[base + k] >> 6], 1);
    __syncthreads();
    for (int i = tid; i < NB; i += 256) hist[seg * NB + i] = bins[i];
}

// ---- phase 2: parallel scan of hist over segs ------------------------------

__global__ void k_psumA(const int* __restrict__ hist, int* __restrict__ psum) {
    int bin = blockIdx.x * 256 + threadIdx.x;
    int ch = blockIdx.y;
    if (bin >= NB) return;
    int s = 0;
    for (int seg = ch * SEGPC; seg < (ch + 1) * SEGPC; ++seg) s += hist[seg * NB + bin];
    psum[ch * NB + bin] = s;
}

__global__ void k_psumB(int* __restrict__ psum, int* __restrict__ bstart) {
    int bin = blockIdx.x * 256 + threadIdx.x;
    if (bin >= NB) return;
    int run = 0;
    #pragma unroll
    for (int ch = 0; ch < NCH; ++ch) {
        int v = psum[ch * NB + bin];
        psum[ch * NB + bin] = run;
        run += v;
    }
    bstart[bin] = run;
}

__global__ void k_scanBkt(int* __restrict__ bstart) {
    __shared__ int lsum[256];
    int t = threadIdx.x;
    const int M = (NB + 255) / 256;   // 7
    int base = t * M;
    int s = 0;
    for (int q = 0; q < M; ++q) { int i = base + q; if (i < NB) s += bstart[i]; }
    lsum[t] = s; __syncthreads();
    for (int off = 1; off < 256; off <<= 1) {
        int add = (t >= off) ? lsum[t - off] : 0;
        __syncthreads(); lsum[t] += add; __syncthreads();
    }
    int run = (t > 0) ? lsum[t - 1] : 0;
    for (int q = 0; q < M; ++q) {
        int i = base + q;
        if (i < NB) { int v = bstart[i]; bstart[i] = run; run += v; }
    }
    if (t == 255) bstart[NB] = run;   // = NE
}

__global__ void k_applyC(int* __restrict__ hist, const int* __restrict__ psum,
                         const int* __restrict__ bstart) {
    int bin = blockIdx.x * 256 + threadIdx.x;
    int ch = blockIdx.y;
    if (bin >= NB) return;
    int run = bstart[bin] + psum[ch * NB + bin];
    for (int seg = ch * SEGPC; seg < (ch + 1) * SEGPC; ++seg) {
        int idx = seg * NB + bin;
        int v = hist[idx];
        hist[idx] = run;
        run += v;
    }
}

// ---- phase 3: LDS-sorted scatter, coalesced int2 writes --------------------
// record: .x = row | (col&63)<<17 ; .y = w_half | bin<<16 (bin bits scrubbed later)

__launch_bounds__(256)
__global__ void k_scatter(const int* __restrict__ row, const int* __restrict__ col,
                          const float* __restrict__ w, const int* __restrict__ hist,
                          int2* __restrict__ bkt) {
    __shared__ int bins[NB];
    __shared__ int cur[NB];
    __shared__ int lsum[256];
    __shared__ int2 sdata[EPS];
    int seg = blockIdx.x, tid = threadIdx.x;
    for (int i = tid; i < NB; i += 256) bins[i] = 0;
    __syncthreads();
    int base = seg * EPS;
    for (int k = tid; k < EPS; k += 256) atomicAdd(&bins[col[base + k] >> 6], 1);
    __syncthreads();
    // block exclusive scan of bins
    const int M = (NB + 255) / 256;
    int lbase = tid * M;
    int s = 0;
    for (int q = 0; q < M; ++q) { int i = lbase + q; if (i < NB) s += bins[i]; }
    lsum[tid] = s; __syncthreads();
    for (int off = 1; off < 256; off <<= 1) {
        int add = (tid >= off) ? lsum[tid - off] : 0;
        __syncthreads(); lsum[tid] += add; __syncthreads();
    }
    int run = (tid > 0) ? lsum[tid - 1] : 0;
    for (int q = 0; q < M; ++q) {
        int i = lbase + q;
        if (i < NB) { int v = bins[i]; bins[i] = run; cur[i] = run; run += v; }
    }
    __syncthreads();
    // place into LDS sorted by bin
    for (int k = tid; k < EPS; k += 256) {
        int e = base + k;
        int r = row[e], c = col[e];
        int bin = c >> 6;
        int pos = atomicAdd(&cur[bin], 1);
        sdata[pos] = make_int2(r | ((c & 63) << 17), f2h_us(w[e]) | (bin << 16));
    }
    __syncthreads();
    // bins[bin] := global_start(seg,bin) - lds_start(bin)
    for (int i = tid; i < NB; i += 256) bins[i] = hist[seg * NB + i] - bins[i];
    __syncthreads();
    for (int j = tid; j < EPS; j += 256) {
        int2 d = sdata[j];
        int bin = ((unsigned)d.y) >> 16;
        bkt[bins[bin] + j] = d;
    }
}

// ---- phase 4: per-bucket refine to node order (coalesced write-back) -------

__launch_bounds__(256)
__global__ void k_refine(const int* __restrict__ bstart, int2* __restrict__ bkt,
                         float* __restrict__ dinv, int* __restrict__ ns) {
    __shared__ int cnt[NPB];
    __shared__ int cur[NPB];
    __shared__ float wdeg[NPB];
    __shared__ int2 sorted[CAP];
    int b = blockIdx.x, tid = threadIdx.x;
    int s = bstart[b], e = bstart[b + 1];
    int size = e - s; if (size > CAP) size = CAP;   // 45-sigma guard, never hit
    if (tid < NPB) { cnt[tid] = 0; wdeg[tid] = 1.0f; }   // self-loop weight
    __syncthreads();
    for (int k = tid; k < size; k += 256) {
        int2 d = bkt[s + k];
        int cl = (d.x >> 17) & 63;
        atomicAdd(&cnt[cl], 1);
        atomicAdd(&wdeg[cl], h2f_lo(d.y));
    }
    __syncthreads();
    int v = (tid < NPB) ? cnt[tid] : 0;
    for (int off = 1; off < NPB; off <<= 1) {
        int add = (tid >= off && tid < NPB) ? cnt[tid - off] : 0;
        __syncthreads();
        if (tid < NPB) cnt[tid] += add;
        __syncthreads();
    }
    if (tid < NPB) {
        int excl = cnt[tid] - v;
        cur[tid] = excl;
        int node = b * NPB + tid;
        if (node < NN) { ns[node] = s + excl; dinv[node] = rsqrtf(wdeg[tid]); }
    }
    if (b == NB - 1 && tid == 0) ns[NN] = e;
    __syncthreads();
    for (int k = tid; k < size; k += 256) {
        int2 d = bkt[s + k];
        int cl = (d.x >> 17) & 63;
        int pos = atomicAdd(&cur[cl], 1);
        sorted[pos] = make_int2(d.x & 0x1FFFF, d.y & 0xFFFF);
    }
    __syncthreads();
    for (int k = tid; k < size; k += 256) bkt[s + k] = sorted[k];
}

// ---- x @ W1, pre-scaled by dinv, fp16 out ----------------------------------
// thread = node (all 16 cols in VGPR accs), W1 via wave-uniform s_load (scalar
// pipe, zero LDS / zero VALU cost), x streamed per-lane from global with L1
// line reuse (16 B/iter per lane, 128 B line = 8-iter reuse window).
// K split in halves across the block's wave-pairs (3128 waves total, ~3/SIMD),
// combined through an 8 KB [16][128] LDS buffer (conflict-free layout).

__launch_bounds__(256)
__global__ void k_xw(const float* __restrict__ x, const float* __restrict__ W1,
                     const float* __restrict__ dinv, int2* __restrict__ xws) {
    __shared__ float sacc[16][128];      // 8 KB
    int tid = threadIdx.x;
    int h = tid >> 7;                    // k-half; uniform per wave (waves 0,1=0; 2,3=1)
    int ln = tid & 127;
    int n = blockIdx.x * 128 + ln;
    int nc = (n < NN) ? n : NN - 1;      // clamp OOB lanes (stores predicated below)
    const float4* xr = (const float4*)(x + (long)nc * FIN) + h * 38;
    const float* wp = rfl_cfp(W1 + h * 38 * 4 * HID);   // uniform SGPR base
    int nf4 = 38 - h;                    // h0: f4 0..37 (k 0..151); h1: f4 38..74 (k 152..299)
    float a[16];
    #pragma unroll
    for (int j = 0; j < 16; ++j) a[j] = 0.f;
    #pragma unroll 4
    for (int q = 0; q < nf4; ++q) {
        float4 xv = xr[q];
        const float* wk = wp + q * 4 * HID;
        #pragma unroll
        for (int j = 0; j < 16; ++j) a[j] = fmaf(xv.x, wk[0 * HID + j], a[j]);
        #pragma unroll
        for (int j = 0; j < 16; ++j) a[j] = fmaf(xv.y, wk[1 * HID + j], a[j]);
        #pragma unroll
        for (int j = 0; j < 16; ++j) a[j] = fmaf(xv.z, wk[2 * HID + j], a[j]);
        #pragma unroll
        for (int j = 0; j < 16; ++j) a[j] = fmaf(xv.w, wk[3 * HID + j], a[j]);
    }
    if (h) {
        #pragma unroll
        for (int j = 0; j < 16; ++j) sacc[j][ln] = a[j];   // consecutive lanes -> consecutive words
    }
    __syncthreads();
    if (!h && n < NN) {
        float di = dinv[n];
        unsigned p[8];
        #pragma unroll
        for (int i = 0; i < 8; ++i) {
            float v0 = di * (a[2 * i]     + sacc[2 * i][ln]);
            float v1 = di * (a[2 * i + 1] + sacc[2 * i + 1][ln]);
            p[i] = (unsigned)f2h_us(v0) | ((unsigned)f2h_us(v1) << 16);
        }
        uint4* o = (uint4*)xws + (long)n * 2;   // 32 B/node, wave covers contiguous 2 KB
        o[0] = make_uint4(p[0], p[1], p[2], p[3]);
        o[1] = make_uint4(p[4], p[5], p[6], p[7]);
    }
}

// ---- layer 1 pull-gather, fused b1/relu/@W2 --------------------------------

__global__ void k_gather1(const int* __restrict__ ns, const int2* __restrict__ bkt,
                          const unsigned short* __restrict__ xwsh,
                          const float* __restrict__ dinv, const float* __restrict__ b1,
                          const float* __restrict__ W2, unsigned short* __restrict__ hw2s) {
    __shared__ float w2s[HID * NC];
    __shared__ float b1s[HID];
    if (threadIdx.x < HID * NC) w2s[threadIdx.x] = W2[threadIdx.x];
    if (threadIdx.x < HID) b1s[threadIdx.x] = b1[threadIdx.x];
    __syncthreads();
    int t = blockIdx.x * 256 + threadIdx.x;
    int i = t >> 4, c = t & 15;
    int s = ns[i], e = ns[i + 1];
    float acc = 0.f;
    int k = s;
    for (; k + 4 <= e; k += 4) {
        int2 e0 = bkt[k], e1 = bkt[k + 1], e2 = bkt[k + 2], e3 = bkt[k + 3];
        __half_raw h0; h0.x = xwsh[e0.x * HID + c];
        __half_raw h1; h1.x = xwsh[e1.x * HID + c];
        __half_raw h2; h2.x = xwsh[e2.x * HID + c];
        __half_raw h3; h3.x = xwsh[e3.x * HID + c];
        acc = fmaf(h2f_lo(e0.y), __half2float(*(__half*)&h0), acc);
        acc = fmaf(h2f_lo(e1.y), __half2float(*(__half*)&h1), acc);
        acc = fmaf(h2f_lo(e2.y), __half2float(*(__half*)&h2), acc);
        acc = fmaf(h2f_lo(e3.y), __half2float(*(__half*)&h3), acc);
    }
    for (; k < e; ++k) {
        int2 e0 = bkt[k];
        __half_raw h0; h0.x = xwsh[e0.x * HID + c];
        acc = fmaf(h2f_lo(e0.y), __half2float(*(__half*)&h0), acc);
    }
    { __half_raw hs; hs.x = xwsh[i * HID + c]; acc += __half2float(*(__half*)&hs); }
    float dc = dinv[i];
    float h = fmaxf(fmaf(dc, acc, b1s[c]), 0.f);
    float acc2 = 0.f;
    int jj = (c < NC) ? c : 0;
    #pragma unroll
    for (int k2 = 0; k2 < HID; ++k2) {
        float hk = __shfl(h, k2, HID);
        acc2 = fmaf(hk, w2s[k2 * NC + jj], acc2);
    }
    if (c < NC) hw2s[i * NC + c] = (unsigned short)f2h_us(dc * acc2);
}

// ---- layer 2 pull-gather, fused b2/log_softmax -----------------------------

__global__ void k_gather2(const int* __restrict__ ns, const int2* __restrict__ bkt,
                          const unsigned short* __restrict__ hw2s,
                          const float* __restrict__ dinv, const float* __restrict__ b2,
                          float* __restrict__ out) {
    int t = blockIdx.x * 256 + threadIdx.x;
    int i = t >> 4, j = t & 15;
    int s = ns[i], e = ns[i + 1];
    float v;
    if (j < NC) {
        float acc = 0.f;
        int k = s;
        for (; k + 4 <= e; k += 4) {
            int2 e0 = bkt[k], e1 = bkt[k + 1], e2 = bkt[k + 2], e3 = bkt[k + 3];
            __half_raw h0; h0.x = hw2s[e0.x * NC + j];
            __half_raw h1; h1.x = hw2s[e1.x * NC + j];
            __half_raw h2; h2.x = hw2s[e2.x * NC + j];
            __half_raw h3; h3.x = hw2s[e3.x * NC + j];
            acc = fmaf(h2f_lo(e0.y), __half2float(*(__half*)&h0), acc);
            acc = fmaf(h2f_lo(e1.y), __half2float(*(__half*)&h1), acc);
            acc = fmaf(h2f_lo(e2.y), __half2float(*(__half*)&h2), acc);
            acc = fmaf(h2f_lo(e3.y), __half2float(*(__half*)&h3), acc);
        }
        for (; k < e; ++k) {
            int2 e0 = bkt[k];
            __half_raw h0; h0.x = hw2s[e0.x * NC + j];
            acc = fmaf(h2f_lo(e0.y), __half2float(*(__half*)&h0), acc);
        }
        { __half_raw hs; hs.x = hw2s[i * NC + j]; acc += __half2float(*(__half*)&hs); }
        v = fmaf(dinv[i], acc, b2[j]);
    } else {
        v = -1e30f;
    }
    float m = v;
    #pragma unroll
    for (int mask = 8; mask > 0; mask >>= 1) m = fmaxf(m, __shfl_xor(m, mask, HID));
    float ev = (j < NC) ? __expf(v - m) : 0.f;
    float ssum = ev;
    #pragma unroll
    for (int mask = 8; mask > 0; mask >>= 1) ssum += __shfl_xor(ssum, mask, HID);
    if (j < NC) out[(long)i * NC + j] = v - m - __logf(ssum);
}

// ---- launch -----------------------------------------------------------------

extern "C" void kernel_launch(void* const* d_in, const int* in_sizes, int n_in,
                              void* d_out, int out_size, void* d_ws, size_t ws_size,
                              hipStream_t stream) {
    const float* x  = (const float*)d_in[0];
    const int*   ei = (const int*)d_in[1];
    const float* ew = (const float*)d_in[2];
    const float* W1 = (const float*)d_in[3];
    const float* b1 = (const float*)d_in[4];
    const float* W2 = (const float*)d_in[5];
    const float* b2 = (const float*)d_in[6];
    float* out = (float*)d_out;

    const int* row = ei;
    const int* col = ei + NE;

    // workspace (words); xws overlays hist (dead after k_scatter)
    int*   hist   = (int*)d_ws;                    // NSEG*NB = 800,256
    int*   psum   = hist + NSEG * NB;              // NCH*NB  = 12,504
    int*   bstart = psum + NCH * NB;               // NB+1    = 1,564
    float* dinv   = (float*)(bstart + NB + 1);     // 100,000
    int*   ns     = (int*)(dinv + NN);             // 100,001
    size_t o = (size_t)(NSEG * NB) + NCH * NB + (NB + 1) + NN + (NN + 1);
    o = (o + 1) & ~(size_t)1;                      // 8B align for int2
    int2*  bkt    = (int2*)((int*)d_ws + o);       // NE int2 = 6,400,000 w
    unsigned short* hw2s = (unsigned short*)(bkt + NE);   // NN*NC halves = 500,000 w
    int2*  xws    = (int2*)hist;                   // NN*4 int2 = 800,000 w overlay
    // total ~= 7,914,326 words = 31.7 MB

    k_hist<<<NSEG, 256, 0, stream>>>(col, hist);
    k_psumA<<<dim3((NB + 255) / 256, NCH), 256, 0, stream>>>(hist, psum);
    k_psumB<<<(NB + 255) / 256, 256, 0, stream>>>(psum, bstart);
    k_scanBkt<<<1, 256, 0, stream>>>(bstart);
    k_applyC<<<dim3((NB + 255) / 256, NCH), 256, 0, stream>>>(hist, psum, bstart);
    k_scatter<<<NSEG, 256, 0, stream>>>(row, col, ew, hist, bkt);
    k_refine<<<NB, 256, 0, stream>>>(bstart, bkt, dinv, ns);

    k_xw<<<(NN + 127) / 128, 256, 0, stream>>>(x, W1, dinv, xws);
    k_gather1<<<(NN * 16) / 256, 256, 0, stream>>>(ns, bkt, (const unsigned short*)xws,
                                                   dinv, b1, W2, hw2s);
    k_gather2<<<(NN * 16) / 256, 256, 0, stream>>>(ns, bkt, hw2s, dinv, b2, out);
}

// Round 4
// 404.090 us; speedup vs baseline: 1.1437x; 1.1437x over previous
//
#include <hip/hip_runtime.h>
#include <hip/hip_fp16.h>

#define NN 100000
#define NE 3200000
#define FIN 300
#define HID 16
#define NC 10

#define NPB 64                  // nodes per bucket
#define NB 1563                 // ceil(NN / NPB)
#define NSEG 512                // edge segments
#define EPS (NE / NSEG)         // 6250 edges per segment
#define NCH 8                   // chunks for the seg-scan
#define SEGPC (NSEG / NCH)      // 64 segs per chunk
#define CAP 4096                // max bucket size (mean 2048, sd ~45)

#define NTILE 6250              // NN / 16 node-tiles for MFMA k_xw

typedef __fp16 h2 __attribute__((ext_vector_type(2)));
typedef __fp16 h8 __attribute__((ext_vector_type(8)));
typedef float f32x4 __attribute__((ext_vector_type(4)));

__device__ __forceinline__ float h2f_lo(int y) {
    __half_raw hr; hr.x = (unsigned short)(y & 0xFFFF);
    __half h; *(__half_raw*)&h = hr;
    return __half2float(h);
}
__device__ __forceinline__ int f2h_us(float f) {
    __half h = __float2half(f);
    return (int)(*(__half_raw*)&h).x;
}

// ---- phase 1: per-segment histogram over buckets ---------------------------

__global__ void k_hist(const int* __restrict__ col, int* __restrict__ hist) {
    __shared__ int bins[NB];
    int seg = blockIdx.x, tid = threadIdx.x;
    for (int i = tid; i < NB; i += 256) bins[i] = 0;
    __syncthreads();
    int base = seg * EPS;
    for (int k = tid; k < EPS; k += 256) atomicAdd(&bins[col[base + k] >> 6], 1);
    __syncthreads();
    for (int i = tid; i < NB; i += 256) hist[seg * NB + i] = bins[i];
}

// ---- phase 2: parallel scan of hist over segs ------------------------------

__global__ void k_psumA(const int* __restrict__ hist, int* __restrict__ psum) {
    int bin = blockIdx.x * 256 + threadIdx.x;
    int ch = blockIdx.y;
    if (bin >= NB) return;
    int s = 0;
    for (int seg = ch * SEGPC; seg < (ch + 1) * SEGPC; ++seg) s += hist[seg * NB + bin];
    psum[ch * NB + bin] = s;
}

__global__ void k_psumB(int* __restrict__ psum, int* __restrict__ bstart) {
    int bin = blockIdx.x * 256 + threadIdx.x;
    if (bin >= NB) return;
    int run = 0;
    #pragma unroll
    for (int ch = 0; ch < NCH; ++ch) {
        int v = psum[ch * NB + bin];
        psum[ch * NB + bin] = run;
        run += v;
    }
    bstart[bin] = run;
}

__global__ void k_scanBkt(int* __restrict__ bstart) {
    __shared__ int lsum[256];
    int t = threadIdx.x;
    const int M = (NB + 255) / 256;   // 7
    int base = t * M;
    int s = 0;
    for (int q = 0; q < M; ++q) { int i = base + q; if (i < NB) s += bstart[i]; }
    lsum[t] = s; __syncthreads();
    for (int off = 1; off < 256; off <<= 1) {
        int add = (t >= off) ? lsum[t - off] : 0;
        __syncthreads(); lsum[t] += add; __syncthreads();
    }
    int run = (t > 0) ? lsum[t - 1] : 0;
    for (int q = 0; q < M; ++q) {
        int i = base + q;
        if (i < NB) { int v = bstart[i]; bstart[i] = run; run += v; }
    }
    if (t == 255) bstart[NB] = run;   // = NE
}

__global__ void k_applyC(int* __restrict__ hist, const int* __restrict__ psum,
                         const int* __restrict__ bstart) {
    int bin = blockIdx.x * 256 + threadIdx.x;
    int ch = blockIdx.y;
    if (bin >= NB) return;
    int run = bstart[bin] + psum[ch * NB + bin];
    for (int seg = ch * SEGPC; seg < (ch + 1) * SEGPC; ++seg) {
        int idx = seg * NB + bin;
        int v = hist[idx];
        hist[idx] = run;
        run += v;
    }
}

// ---- phase 3: LDS-sorted scatter, coalesced int2 writes --------------------
// record: .x = row | (col&63)<<17 ; .y = w_half | bin<<16 (bin bits scrubbed later)

__launch_bounds__(256)
__global__ void k_scatter(const int* __restrict__ row, const int* __restrict__ col,
                          const float* __restrict__ w, const int* __restrict__ hist,
                          int2* __restrict__ bkt) {
    __shared__ int bins[NB];
    __shared__ int cur[NB];
    __shared__ int lsum[256];
    __shared__ int2 sdata[EPS];
    int seg = blockIdx.x, tid = threadIdx.x;
    for (int i = tid; i < NB; i += 256) bins[i] = 0;
    __syncthreads();
    int base = seg * EPS;
    for (int k = tid; k < EPS; k += 256) atomicAdd(&bins[col[base + k] >> 6], 1);
    __syncthreads();
    // block exclusive scan of bins
    const int M = (NB + 255) / 256;
    int lbase = tid * M;
    int s = 0;
    for (int q = 0; q < M; ++q) { int i = lbase + q; if (i < NB) s += bins[i]; }
    lsum[tid] = s; __syncthreads();
    for (int off = 1; off < 256; off <<= 1) {
        int add = (tid >= off) ? lsum[tid - off] : 0;
        __syncthreads(); lsum[tid] += add; __syncthreads();
    }
    int run = (tid > 0) ? lsum[tid - 1] : 0;
    for (int q = 0; q < M; ++q) {
        int i = lbase + q;
        if (i < NB) { int v = bins[i]; bins[i] = run; cur[i] = run; run += v; }
    }
    __syncthreads();
    // place into LDS sorted by bin
    for (int k = tid; k < EPS; k += 256) {
        int e = base + k;
        int r = row[e], c = col[e];
        int bin = c >> 6;
        int pos = atomicAdd(&cur[bin], 1);
        sdata[pos] = make_int2(r | ((c & 63) << 17), f2h_us(w[e]) | (bin << 16));
    }
    __syncthreads();
    // bins[bin] := global_start(seg,bin) - lds_start(bin)
    for (int i = tid; i < NB; i += 256) bins[i] = hist[seg * NB + i] - bins[i];
    __syncthreads();
    for (int j = tid; j < EPS; j += 256) {
        int2 d = sdata[j];
        int bin = ((unsigned)d.y) >> 16;
        bkt[bins[bin] + j] = d;
    }
}

// ---- phase 4: per-bucket refine to node order (coalesced write-back) -------

__launch_bounds__(256)
__global__ void k_refine(const int* __restrict__ bstart, int2* __restrict__ bkt,
                         float* __restrict__ dinv, int* __restrict__ ns) {
    __shared__ int cnt[NPB];
    __shared__ int cur[NPB];
    __shared__ float wdeg[NPB];
    __shared__ int2 sorted[CAP];
    int b = blockIdx.x, tid = threadIdx.x;
    int s = bstart[b], e = bstart[b + 1];
    int size = e - s; if (size > CAP) size = CAP;   // 45-sigma guard, never hit
    if (tid < NPB) { cnt[tid] = 0; wdeg[tid] = 1.0f; }   // self-loop weight
    __syncthreads();
    for (int k = tid; k < size; k += 256) {
        int2 d = bkt[s + k];
        int cl = (d.x >> 17) & 63;
        atomicAdd(&cnt[cl], 1);
        atomicAdd(&wdeg[cl], h2f_lo(d.y));
    }
    __syncthreads();
    int v = (tid < NPB) ? cnt[tid] : 0;
    for (int off = 1; off < NPB; off <<= 1) {
        int add = (tid >= off && tid < NPB) ? cnt[tid - off] : 0;
        __syncthreads();
        if (tid < NPB) cnt[tid] += add;
        __syncthreads();
    }
    if (tid < NPB) {
        int excl = cnt[tid] - v;
        cur[tid] = excl;
        int node = b * NPB + tid;
        if (node < NN) { ns[node] = s + excl; dinv[node] = rsqrtf(wdeg[tid]); }
    }
    if (b == NB - 1 && tid == 0) ns[NN] = e;
    __syncthreads();
    for (int k = tid; k < size; k += 256) {
        int2 d = bkt[s + k];
        int cl = (d.x >> 17) & 63;
        int pos = atomicAdd(&cur[cl], 1);
        sorted[pos] = make_int2(d.x & 0x1FFFF, d.y & 0xFFFF);
    }
    __syncthreads();
    for (int k = tid; k < size; k += 256) bkt[s + k] = sorted[k];
}

// ---- x @ W1 via MFMA (f16 inputs, fp32 acc), pre-scaled by dinv, fp16 out --
// Wave tile = 16 nodes x 16 cols over K=320 (zero-padded from 300): 10x
// v_mfma_f32_16x16x32_f16. W1 pre-converted once per block into frag-ordered
// LDS (10 KB) -> B operand = 1 ds_read_b128 per K-step. A streamed from
// global: lane (row=lane&15, kblk=lane>>4) reads 32 B contiguous per step --
// every touched line fully consumed by the same instruction pair.
// fp16 RTZ conversion: sign-following relative error ~2^-11/factor -> ~0.1%
// relative on the K=300 dot product; output is stored fp16 anyway.

__launch_bounds__(256)
__global__ void k_xw(const float* __restrict__ x, const float* __restrict__ W1,
                     const float* __restrict__ dinv, int2* __restrict__ xws) {
    __shared__ h8 bfrag[10][64];        // 10 KB, frag-ordered W1 in f16
    int tid = threadIdx.x;
    // stage + convert W1: entry (s,l): col=l&15, k = 32s + 8*(l>>4) + j
    for (int e2 = tid; e2 < 640; e2 += 256) {
        int s = e2 >> 6, l = e2 & 63;
        int g = l >> 4, c = l & 15;
        int kb = 32 * s + 8 * g;
        float f[8];
        #pragma unroll
        for (int j = 0; j < 8; ++j) {
            int k = kb + j;
            f[j] = (k < FIN) ? W1[k * HID + c] : 0.f;
        }
        h2 q0 = __builtin_amdgcn_cvt_pkrtz(f[0], f[1]);
        h2 q1 = __builtin_amdgcn_cvt_pkrtz(f[2], f[3]);
        h2 q2 = __builtin_amdgcn_cvt_pkrtz(f[4], f[5]);
        h2 q3 = __builtin_amdgcn_cvt_pkrtz(f[6], f[7]);
        h8 v;
        v[0] = q0[0]; v[1] = q0[1]; v[2] = q1[0]; v[3] = q1[1];
        v[4] = q2[0]; v[5] = q2[1]; v[6] = q3[0]; v[7] = q3[1];
        bfrag[s][l] = v;
    }
    __syncthreads();
    int widx = tid >> 6, lane = tid & 63;
    int g = lane >> 4, rr = lane & 15;
    int gw = blockIdx.x * 4 + widx;
    unsigned short* op = (unsigned short*)xws;
    #pragma unroll 1
    for (int t = 0; t < 2; ++t) {
        int tile = gw * 2 + t;
        if (tile >= NTILE) break;
        int n0 = tile * 16;
        const float* xrow = x + (long)(n0 + rr) * FIN;
        f32x4 acc = {0.f, 0.f, 0.f, 0.f};
        #pragma unroll
        for (int s = 0; s < 9; ++s) {
            int k0 = 32 * s + 8 * g;
            f32x4 u0 = *(const f32x4*)(xrow + k0);
            f32x4 u1 = *(const f32x4*)(xrow + k0 + 4);
            h2 p0 = __builtin_amdgcn_cvt_pkrtz(u0[0], u0[1]);
            h2 p1 = __builtin_amdgcn_cvt_pkrtz(u0[2], u0[3]);
            h2 p2 = __builtin_amdgcn_cvt_pkrtz(u1[0], u1[1]);
            h2 p3 = __builtin_amdgcn_cvt_pkrtz(u1[2], u1[3]);
            h8 a;
            a[0] = p0[0]; a[1] = p0[1]; a[2] = p1[0]; a[3] = p1[1];
            a[4] = p2[0]; a[5] = p2[1]; a[6] = p3[0]; a[7] = p3[1];
            acc = __builtin_amdgcn_mfma_f32_16x16x32_f16(a, bfrag[s][lane], acc, 0, 0, 0);
        }
        {   // K tail: k 288..299 valid, 300..319 zero (g=1 upper half, g>=2 all)
            int k0 = 288 + 8 * g;
            f32x4 z = {0.f, 0.f, 0.f, 0.f};
            f32x4 u0 = (g < 2) ? *(const f32x4*)(xrow + k0) : z;
            f32x4 u1 = (g == 0) ? *(const f32x4*)(xrow + k0 + 4) : z;
            h2 p0 = __builtin_amdgcn_cvt_pkrtz(u0[0], u0[1]);
            h2 p1 = __builtin_amdgcn_cvt_pkrtz(u0[2], u0[3]);
            h2 p2 = __builtin_amdgcn_cvt_pkrtz(u1[0], u1[1]);
            h2 p3 = __builtin_amdgcn_cvt_pkrtz(u1[2], u1[3]);
            h8 a;
            a[0] = p0[0]; a[1] = p0[1]; a[2] = p1[0]; a[3] = p1[1];
            a[4] = p2[0]; a[5] = p2[1]; a[6] = p3[0]; a[7] = p3[1];
            acc = __builtin_amdgcn_mfma_f32_16x16x32_f16(a, bfrag[9][lane], acc, 0, 0, 0);
        }
        // C/D: col = lane&15 (=rr), row-in-tile = g*4 + r2
        #pragma unroll
        for (int r2 = 0; r2 < 4; ++r2) {
            int node = n0 + g * 4 + r2;
            float di = dinv[node];
            op[(long)node * HID + rr] = (unsigned short)f2h_us(di * acc[r2]);
        }
    }
}

// ---- layer 1 pull-gather, fused b1/relu/@W2 --------------------------------

__global__ void k_gather1(const int* __restrict__ ns, const int2* __restrict__ bkt,
                          const unsigned short* __restrict__ xwsh,
                          const float* __restrict__ dinv, const float* __restrict__ b1,
                          const float* __restrict__ W2, unsigned short* __restrict__ hw2s) {
    __shared__ float w2s[HID * NC];
    __shared__ float b1s[HID];
    if (threadIdx.x < HID * NC) w2s[threadIdx.x] = W2[threadIdx.x];
    if (threadIdx.x < HID) b1s[threadIdx.x] = b1[threadIdx.x];
    __syncthreads();
    int t = blockIdx.x * 256 + threadIdx.x;
    int i = t >> 4, c = t & 15;
    int s = ns[i], e = ns[i + 1];
    float acc = 0.f;
    int k = s;
    for (; k + 4 <= e; k += 4) {
        int2 e0 = bkt[k], e1 = bkt[k + 1], e2 = bkt[k + 2], e3 = bkt[k + 3];
        __half_raw h0; h0.x = xwsh[e0.x * HID + c];
        __half_raw h1; h1.x = xwsh[e1.x * HID + c];
        __half_raw h2; h2.x = xwsh[e2.x * HID + c];
        __half_raw h3; h3.x = xwsh[e3.x * HID + c];
        acc = fmaf(h2f_lo(e0.y), __half2float(*(__half*)&h0), acc);
        acc = fmaf(h2f_lo(e1.y), __half2float(*(__half*)&h1), acc);
        acc = fmaf(h2f_lo(e2.y), __half2float(*(__half*)&h2), acc);
        acc = fmaf(h2f_lo(e3.y), __half2float(*(__half*)&h3), acc);
    }
    for (; k < e; ++k) {
        int2 e0 = bkt[k];
        __half_raw h0; h0.x = xwsh[e0.x * HID + c];
        acc = fmaf(h2f_lo(e0.y), __half2float(*(__half*)&h0), acc);
    }
    { __half_raw hs; hs.x = xwsh[i * HID + c]; acc += __half2float(*(__half*)&hs); }
    float dc = dinv[i];
    float h = fmaxf(fmaf(dc, acc, b1s[c]), 0.f);
    float acc2 = 0.f;
    int jj = (c < NC) ? c : 0;
    #pragma unroll
    for (int k2 = 0; k2 < HID; ++k2) {
        float hk = __shfl(h, k2, HID);
        acc2 = fmaf(hk, w2s[k2 * NC + jj], acc2);
    }
    if (c < NC) hw2s[i * NC + c] = (unsigned short)f2h_us(dc * acc2);
}

// ---- layer 2 pull-gather, fused b2/log_softmax -----------------------------

__global__ void k_gather2(const int* __restrict__ ns, const int2* __restrict__ bkt,
                          const unsigned short* __restrict__ hw2s,
                          const float* __restrict__ dinv, const float* __restrict__ b2,
                          float* __restrict__ out) {
    int t = blockIdx.x * 256 + threadIdx.x;
    int i = t >> 4, j = t & 15;
    int s = ns[i], e = ns[i + 1];
    float v;
    if (j < NC) {
        float acc = 0.f;
        int k = s;
        for (; k + 4 <= e; k += 4) {
            int2 e0 = bkt[k], e1 = bkt[k + 1], e2 = bkt[k + 2], e3 = bkt[k + 3];
            __half_raw h0; h0.x = hw2s[e0.x * NC + j];
            __half_raw h1; h1.x = hw2s[e1.x * NC + j];
            __half_raw h2; h2.x = hw2s[e2.x * NC + j];
            __half_raw h3; h3.x = hw2s[e3.x * NC + j];
            acc = fmaf(h2f_lo(e0.y), __half2float(*(__half*)&h0), acc);
            acc = fmaf(h2f_lo(e1.y), __half2float(*(__half*)&h1), acc);
            acc = fmaf(h2f_lo(e2.y), __half2float(*(__half*)&h2), acc);
            acc = fmaf(h2f_lo(e3.y), __half2float(*(__half*)&h3), acc);
        }
        for (; k < e; ++k) {
            int2 e0 = bkt[k];
            __half_raw h0; h0.x = hw2s[e0.x * NC + j];
            acc = fmaf(h2f_lo(e0.y), __half2float(*(__half*)&h0), acc);
        }
        { __half_raw hs; hs.x = hw2s[i * NC + j]; acc += __half2float(*(__half*)&hs); }
        v = fmaf(dinv[i], acc, b2[j]);
    } else {
        v = -1e30f;
    }
    float m = v;
    #pragma unroll
    for (int mask = 8; mask > 0; mask >>= 1) m = fmaxf(m, __shfl_xor(m, mask, HID));
    float ev = (j < NC) ? __expf(v - m) : 0.f;
    float ssum = ev;
    #pragma unroll
    for (int mask = 8; mask > 0; mask >>= 1) ssum += __shfl_xor(ssum, mask, HID);
    if (j < NC) out[(long)i * NC + j] = v - m - __logf(ssum);
}

// ---- launch -----------------------------------------------------------------

extern "C" void kernel_launch(void* const* d_in, const int* in_sizes, int n_in,
                              void* d_out, int out_size, void* d_ws, size_t ws_size,
                              hipStream_t stream) {
    const float* x  = (const float*)d_in[0];
    const int*   ei = (const int*)d_in[1];
    const float* ew = (const float*)d_in[2];
    const float* W1 = (const float*)d_in[3];
    const float* b1 = (const float*)d_in[4];
    const float* W2 = (const float*)d_in[5];
    const float* b2 = (const float*)d_in[6];
    float* out = (float*)d_out;

    const int* row = ei;
    const int* col = ei + NE;

    // workspace (words); xws overlays hist (dead after k_scatter)
    int*   hist   = (int*)d_ws;                    // NSEG*NB = 800,256
    int*   psum   = hist + NSEG * NB;              // NCH*NB  = 12,504
    int*   bstart = psum + NCH * NB;               // NB+1    = 1,564
    float* dinv   = (float*)(bstart + NB + 1);     // 100,000
    int*   ns     = (int*)(dinv + NN);             // 100,001
    size_t o = (size_t)(NSEG * NB) + NCH * NB + (NB + 1) + NN + (NN + 1);
    o = (o + 1) & ~(size_t)1;                      // 8B align for int2
    int2*  bkt    = (int2*)((int*)d_ws + o);       // NE int2 = 6,400,000 w
    unsigned short* hw2s = (unsigned short*)(bkt + NE);   // NN*NC halves = 500,000 w
    int2*  xws    = (int2*)hist;                   // NN*4 int2 = 800,000 w overlay
    // total ~= 7,914,326 words = 31.7 MB

    k_hist<<<NSEG, 256, 0, stream>>>(col, hist);
    k_psumA<<<dim3((NB + 255) / 256, NCH), 256, 0, stream>>>(hist, psum);
    k_psumB<<<(NB + 255) / 256, 256, 0, stream>>>(psum, bstart);
    k_scanBkt<<<1, 256, 0, stream>>>(bstart);
    k_applyC<<<dim3((NB + 255) / 256, NCH), 256, 0, stream>>>(hist, psum, bstart);
    k_scatter<<<NSEG, 256, 0, stream>>>(row, col, ew, hist, bkt);
    k_refine<<<NB, 256, 0, stream>>>(bstart, bkt, dinv, ns);

    // 782 blocks x 4 waves x 2 tiles = 6256 >= 6250 tiles
    k_xw<<<782, 256, 0, stream>>>(x, W1, dinv, xws);
    k_gather1<<<(NN * 16) / 256, 256, 0, stream>>>(ns, bkt, (const unsigned short*)xws,
                                                   dinv, b1, W2, hw2s);
    k_gather2<<<(NN * 16) / 256, 256, 0, stream>>>(ns, bkt, hw2s, dinv, b2, out);
}